// Round 18
// baseline (460.650 us; speedup 1.0000x reference)
//
#include <hip/hip_runtime.h>

// CRF Viterbi forward decode — R12: R11 step body + 8-wave batch packing.
// potentials: [1024, 512, 48] f32, transition: [48, 48] f32.
// out = backpointers [1024, 511, 48] (float-encoded) ++ scores [1024, 48] f32.
//
// R11 post-mortem (226 us, VGPR=64, VALUBusy 65.7%): fused tournament did
// NOT remove the inflation; three different step bodies (R6/R8/R11) all
// land at 965-1071 cyc/step. The step body is no longer the lever: with
// 1024 single-wave blocks on 256 CUs we sit at exactly 1 wave/SIMD, so
// ~35% stall + allocator rematerialization overhead have nothing to hide
// under.
//
// R12 lever (ONE change): pack 8 INDEPENDENT batch-waves per 512-thread
// block -> 128 blocks -> 1 block/CU on 128 CUs -> 2 waves/SIMD. Waves
// share NOTHING (own batch, own stv row, own wave_barrier; no
// __syncthreads) — this is not R7 (which split one batch across waves
// and paid combine+barrier+register starvation). Wall/step model:
// max(2x697 busy, 697+364 latency) = 1394 cyc / 2 wave-steps -> ~1.5x.
// Register budget: need ~80, cap 256 at 2 waves/EU -> no starvation.
// Lanes 48-63 per wave: j clamped to 47 -> identical arithmetic to lane
// 47, duplicate same-address same-data stores (benign, single instr).
//
// Step body byte-identical to R11: 12 ds_read_b128 broadcast -> 48 adds
// -> 47-merge fused (value,index) tournament (exact first-occurrence
// argmax) -> myst -> ds_write -> bp store -> wave_barrier.

constexpr int B_ = 1024;
constexpr int T_ = 512;
constexpr int K_ = 48;
constexpr int C_ = 6;    // steps t=2..511 -> 510 = 6 * 85, no remainder
constexpr int NW_ = 8;   // independent batch-waves per block

__global__ __launch_bounds__(512, 2) void crf_viterbi_kernel(
    const float* __restrict__ pot,
    const float* __restrict__ trans,
    float* __restrict__ out)
{
    const int w    = threadIdx.x >> 6;          // wave id 0..7
    const int lane = threadIdx.x & 63;
    const int j    = (lane < K_) ? lane : (K_ - 1);  // clamped dest tag
    const int b    = blockIdx.x * NW_ + w;      // this wave's batch

    // Per-wave state rows; wave w owns stv[w*K_ .. w*K_+47]. 192 B rows
    // (16B-aligned). No cross-wave sharing, no __syncthreads anywhere.
    __shared__ __align__(16) float stv[NW_ * K_];
    float* svbase = stv + w * K_;

    // Transition column j -> 48 VGPRs (reused 511 times).
    float tcol[K_];
    #pragma unroll
    for (int i = 0; i < K_; ++i) tcol[i] = trans[i * K_ + j];

    const float* pp = pot + (size_t)b * T_ * K_ + j;
    float* bpp      = out + (size_t)b * (T_ - 1) * K_ + j;   // walking bp ptr
    float* scout    = out + (size_t)B_ * (T_ - 1) * K_ + (size_t)b * K_ + j;

    // t = 0 state. (Lanes 48-63 compute lane 47's values; duplicate writes
    // carry identical data -> benign.)
    float myst = pp[0];
    svbase[j] = myst;
    __builtin_amdgcn_wave_barrier();

    // Rotating bp store-data registers: slot u redefined only 6 steps after
    // its store -> no per-step vmcnt store-ack WAR stall.
    float bpf0 = 0.0f, bpf1 = 0.0f, bpf2 = 0.0f,
          bpf3 = 0.0f, bpf4 = 0.0f, bpf5 = 0.0f;

// One merge of the (value,index) tournament. Left wins ties (>=) ->
// first-occurrence argmax. max + cmp independent; cndmask depends on cmp.
#define MRG(VD, XD, VA, XA, VB, XB)                                            \
    do {                                                                       \
        bool c_ = (VA) >= (VB);                                                \
        VD = fmaxf((VA), (VB));                                                \
        XD = c_ ? (XA) : (XB);                                                 \
    } while (0)

// One step t (t=1..511): ds_read S(t-1) -> cand -> fused tournament
// (mm, xx in one pass) -> myst -> ds_write -> bp row (t-1) store -> fence.
#define STEP(PCUR, BPV)                                                        \
    do {                                                                       \
        /* (1) Batched broadcast reads — 12 x ds_read_b128, static offsets. */ \
        float4 sv[12];                                                         \
        const float4* stv4 = (const float4*)svbase;                            \
        _Pragma("unroll")                                                      \
        for (int c = 0; c < 12; ++c) sv[c] = stv4[c];                          \
        /* (2) 48 candidates (each consumed once, by its leaf merge). */       \
        float cand[K_];                                                        \
        _Pragma("unroll")                                                      \
        for (int c = 0; c < 12; ++c) {                                         \
            cand[4 * c + 0] = sv[c].x + tcol[4 * c + 0];                       \
            cand[4 * c + 1] = sv[c].y + tcol[4 * c + 1];                       \
            cand[4 * c + 2] = sv[c].z + tcol[4 * c + 2];                       \
            cand[4 * c + 3] = sv[c].w + tcol[4 * c + 3];                       \
        }                                                                      \
        /* (3) Fused tournament: 47 merges, depth 6, single pass. Leaf        \
           indices 2k/2k+1 are VOP3 inline constants (<= 47 < 64). */          \
        float v1[24]; int x1[24];                                              \
        _Pragma("unroll")                                                      \
        for (int k = 0; k < 24; ++k)                                           \
            MRG(v1[k], x1[k], cand[2 * k], 2 * k, cand[2 * k + 1], 2 * k + 1); \
        float v2[12]; int x2[12];                                              \
        _Pragma("unroll")                                                      \
        for (int k = 0; k < 12; ++k)                                           \
            MRG(v2[k], x2[k], v1[2 * k], x1[2 * k], v1[2 * k + 1], x1[2 * k + 1]); \
        float v3[6]; int x3[6];                                                \
        _Pragma("unroll")                                                      \
        for (int k = 0; k < 6; ++k)                                            \
            MRG(v3[k], x3[k], v2[2 * k], x2[2 * k], v2[2 * k + 1], x2[2 * k + 1]); \
        float v4[3]; int x4[3];                                                \
        _Pragma("unroll")                                                      \
        for (int k = 0; k < 3; ++k)                                            \
            MRG(v4[k], x4[k], v3[2 * k], x3[2 * k], v3[2 * k + 1], x3[2 * k + 1]); \
        float v5; int x5;                                                      \
        MRG(v5, x5, v4[0], x4[0], v4[1], x4[1]);                               \
        float mm; int xx;                                                      \
        MRG(mm, xx, v5, x5, v4[2], x4[2]);                                     \
        /* (4) Value recurrence first (critical path), then bp store. */       \
        myst = (PCUR) + mm;                                                    \
        svbase[j] = myst;                                                      \
        BPV = (float)xx;                                                       \
        *bpp = BPV;            /* bp row t-1 */                                \
        bpp += K_;                                                             \
        __builtin_amdgcn_wave_barrier();                                       \
    } while (0)

    // Potential for t=1 and prefetch t=2..7 (R6's measured-good clamp form).
    float p1 = pp[(size_t)1 * K_];
    float pbuf[C_];
    #pragma unroll
    for (int u = 0; u < C_; ++u) pbuf[u] = pp[(size_t)(2 + u) * K_];

    // t = 1: stores bp row 0.
    STEP(p1, bpf5);

    for (int t0 = 2; t0 < T_; t0 += C_) {   // t0 = 2, 8, ..., 506 (85 chunks)
        float pc[C_];
        #pragma unroll
        for (int u = 0; u < C_; ++u) pc[u] = pbuf[u];

        // Prefetch next chunk (clamped; dup loads harmless; 6-step slack,
        // no vmcnt-draining barriers to expose the latency).
        #pragma unroll
        for (int u = 0; u < C_; ++u) {
            int tn = t0 + C_ + u;
            if (tn > T_ - 1) tn = T_ - 1;
            pbuf[u] = pp[(size_t)tn * K_];
        }

        STEP(pc[0], bpf0);
        STEP(pc[1], bpf1);
        STEP(pc[2], bpf2);
        STEP(pc[3], bpf3);
        STEP(pc[4], bpf4);
        STEP(pc[5], bpf5);
    }

    // Keep rotating store regs live (defeat DSE of the rotation).
    asm volatile("" :: "v"(bpf0), "v"(bpf1), "v"(bpf2),
                       "v"(bpf3), "v"(bpf4), "v"(bpf5));

    // Final Viterbi scores (S(511)).
    *scout = myst;
#undef STEP
#undef MRG
}

extern "C" void kernel_launch(void* const* d_in, const int* in_sizes, int n_in,
                              void* d_out, int out_size, void* d_ws, size_t ws_size,
                              hipStream_t stream) {
    const float* pot   = (const float*)d_in[0];
    const float* trans = (const float*)d_in[1];
    float* out         = (float*)d_out;
    crf_viterbi_kernel<<<dim3(B_ / NW_), dim3(64 * NW_), 0, stream>>>(pot, trans, out);
}